// Round 5
// baseline (798.079 us; speedup 1.0000x reference)
//
#include <hip/hip_runtime.h>

#define B_ 1024
#define S_ 128
#define E_ 256
#define H_ 8
#define D_ 64
#define HD_ 512

typedef short s16x8 __attribute__((ext_vector_type(8)));   // 8 bf16 (guide §3)
typedef float f32x4 __attribute__((ext_vector_type(4)));
typedef unsigned int u32x4 __attribute__((ext_vector_type(4)));
typedef unsigned short u16;
typedef unsigned int u32;

struct U16x8 { u16 v[8]; };

__device__ __forceinline__ u16 f2bf(float f) {
  u32 u = __float_as_uint(f);
  u += 0x7FFFu + ((u >> 16) & 1u);   // round-to-nearest-even
  return (u16)(u >> 16);
}

// pack two f32 -> one u32 of 2x bf16 (lo = s0, hi = s1); no builtin on gfx950
__device__ __forceinline__ u32 cvtpk_bf16(float lo, float hi) {
  u32 r;
  asm("v_cvt_pk_bf16_f32 %0, %1, %2" : "=v"(r) : "v"(lo), "v"(hi));
  return r;
}

// async DMA one 32 KiB weight slice (frag-linear) into LDS: 512 thr x 4 x 16B
__device__ __forceinline__ void dma_w(const u16* __restrict__ WF, int base8,
                                      u16* dst, int tid) {
  const char* g = (const char*)WF + (size_t)base8 * 32768 + (size_t)tid * 16;
  char* l = (char*)dst + tid * 16;
#pragma unroll
  for (int j = 0; j < 4; ++j)
    __builtin_amdgcn_global_load_lds(
        (const __attribute__((address_space(1))) void*)(g + j * 8192),
        (__attribute__((address_space(3))) void*)(l + j * 8192), 16, 0, 0);
}

// ---------------------------------------------------------------------------
// Dtype probe: decide whether inputs are packed bf16 or float32.
// ---------------------------------------------------------------------------
__global__ __launch_bounds__(256) void probe_dtype(const u32* __restrict__ x,
                                                   u32* __restrict__ flag) {
  __shared__ int cnt;
  if (threadIdx.x == 0) cnt = 0;
  __syncthreads();
  u32 w = x[threadIdx.x];
  u32 e = (w >> 7) & 0xFFu;
  if (e > 96u && e < 160u) atomicAdd(&cnt, 1);
  __syncthreads();
  if (threadIdx.x == 0) flag[0] = (cnt > 128) ? 1u : 0u;
}

// ---------------------------------------------------------------------------
// Repack the four (E x HD) weights into bf16 MFMA B-fragment order:
// WF[(((w*8+h)*8+ks)*4+tc)*64+lane][j] = W_w[ks*32+(lane>>4)*8+j][h*64+tc*16+(lane&15)]
// Each (w,h) slice is a contiguous 32 KiB block -> DMA-able with global_load_lds.
// ---------------------------------------------------------------------------
__global__ __launch_bounds__(256) void repack_w(
    const void* __restrict__ wqv, const void* __restrict__ wkv,
    const void* __restrict__ wvv, const void* __restrict__ wrv,
    const u32* __restrict__ flag, u16* __restrict__ wf) {
  bool isbf = (flag[0] != 0u);
  int t = blockIdx.x * 256 + threadIdx.x;   // 65536 threads total
  int lane = t & 63;
  int tc   = (t >> 6) & 3;
  int ks   = (t >> 8) & 7;
  int h    = (t >> 11) & 7;
  int w    = (t >> 14) & 3;
  const void* srcv = (w == 0) ? wqv : (w == 1) ? wkv : (w == 2) ? wvv : wrv;
  int n  = h * D_ + tc * 16 + (lane & 15);
  int e0 = ks * 32 + (lane >> 4) * 8;
  U16x8 tmp;
  if (isbf) {
    const u16* s = (const u16*)srcv;
#pragma unroll
    for (int j = 0; j < 8; ++j) tmp.v[j] = s[(e0 + j) * HD_ + n];
  } else {
    const float* s = (const float*)srcv;
#pragma unroll
    for (int j = 0; j < 8; ++j) tmp.v[j] = f2bf(s[(e0 + j) * HD_ + n]);
  }
  *(u32x4*)(wf + (size_t)t * 8) = *(const u32x4*)tmp.v;
}

// Dual-batch projection from an LDS weight slice: each B-frag read ONCE,
// two MFMAs issued (halves LDS proj traffic per batch — the dominant term).
__device__ __forceinline__ void proj4_lds2(const u16* __restrict__ Wb, int lane,
                                           const s16x8 xf0[8], const s16x8 xf1[8],
                                           f32x4 a0[4], f32x4 a1[4]) {
  const u32x4* w4 = (const u32x4*)Wb + lane;
#pragma unroll
  for (int tc = 0; tc < 4; ++tc) {
    a0[tc] = (f32x4){0.f, 0.f, 0.f, 0.f};
    a1[tc] = (f32x4){0.f, 0.f, 0.f, 0.f};
  }
#pragma unroll
  for (int ks = 0; ks < 8; ++ks) {
#pragma unroll
    for (int tc = 0; tc < 4; ++tc) {
      u32x4 raw = w4[(ks * 4 + tc) * 64];
      s16x8 bfr = *(const s16x8*)&raw;
      a0[tc] = __builtin_amdgcn_mfma_f32_16x16x32_bf16(xf0[ks], bfr, a0[tc], 0, 0, 0);
      a1[tc] = __builtin_amdgcn_mfma_f32_16x16x32_bf16(xf1[ks], bfr, a1[tc], 0, 0, 0);
    }
  }
}

// Fallback (ws too small for WF): gather B-frags from the original layout.
__device__ __forceinline__ void proj4_direct(const void* __restrict__ srcv, bool isbf,
                                             int h, int lane, const s16x8 xfrag[8],
                                             f32x4 acc[4]) {
#pragma unroll
  for (int tc = 0; tc < 4; ++tc) acc[tc] = (f32x4){0.f, 0.f, 0.f, 0.f};
  int e8 = (lane >> 4) * 8;
  int nc = h * D_ + (lane & 15);
#pragma unroll
  for (int ks = 0; ks < 8; ++ks) {
#pragma unroll
    for (int tc = 0; tc < 4; ++tc) {
      U16x8 tmp;
      if (isbf) {
        const u16* s = (const u16*)srcv;
#pragma unroll
        for (int j = 0; j < 8; ++j) tmp.v[j] = s[(ks * 32 + e8 + j) * HD_ + nc + tc * 16];
      } else {
        const float* s = (const float*)srcv;
#pragma unroll
        for (int j = 0; j < 8; ++j) tmp.v[j] = f2bf(s[(ks * 32 + e8 + j) * HD_ + nc + tc * 16]);
      }
      s16x8 bfr = *(const s16x8*)tmp.v;
      acc[tc] = __builtin_amdgcn_mfma_f32_16x16x32_bf16(xfrag[ks], bfr, acc[tc], 0, 0, 0);
    }
  }
}

// Scatter projection C-frags (row=quad*4+r, col=tc*16+col) into A/B-frag-major
// LDS layout — same index formula for Q and K.
__device__ __forceinline__ void scatter_qk(u16* dst, int w, int quad, int col,
                                           const f32x4 acc[4]) {
#pragma unroll
  for (int tc = 0; tc < 4; ++tc) {
    int ks2 = tc >> 1;
    int q2  = (tc & 1) * 2 + (col >> 3);
#pragma unroll
    for (int r = 0; r < 4; ++r)
      dst[(((w * 2 + ks2) * 64) + q2 * 16 + quad * 4 + r) * 8 + (col & 7)] =
          f2bf(acc[tc][r]);
  }
}

// V goes to B-frag-major for O = P@V (k = s', n = d).
__device__ __forceinline__ void scatter_v(u16* Vf, int w, int quad, int col,
                                          const f32x4 acc[4]) {
#pragma unroll
  for (int tc = 0; tc < 4; ++tc)
#pragma unroll
    for (int r = 0; r < 4; ++r) {
      int srow = quad * 4 + r;
      int q2   = (w & 1) * 2 + (srow >> 3);
      Vf[((((w >> 1) * 4 + tc) * 64) + q2 * 16 + col) * 8 + (srow & 7)] =
          f2bf(acc[tc][r]);
    }
}

// S^T = K Q^T (swapped operands) + in-register softmax + P^T bf16 pack.
__device__ __forceinline__ void qk_sm(const u16* __restrict__ Kp, const s16x8 aqb[2],
                                      int lane, u32 wp[8][2], float& linv) {
  f32x4 sacc[8];
#pragma unroll
  for (int tS = 0; tS < 8; ++tS) {
    sacc[tS] = (f32x4){0.f, 0.f, 0.f, 0.f};
#pragma unroll
    for (int k2 = 0; k2 < 2; ++k2) {
      s16x8 bk = *(const s16x8*)(Kp + ((tS * 2 + k2) * 64 + lane) * 8);
      sacc[tS] = __builtin_amdgcn_mfma_f32_16x16x32_bf16(bk, aqb[k2], sacc[tS], 0, 0, 0);
    }
  }
  float m = sacc[0][0];
#pragma unroll
  for (int tS = 0; tS < 8; ++tS)
#pragma unroll
    for (int r = 0; r < 4; ++r) m = fmaxf(m, sacc[tS][r]);
  m = fmaxf(m, __shfl_xor(m, 16));
  m = fmaxf(m, __shfl_xor(m, 32));
  float lsum = 0.f;
#pragma unroll
  for (int tS = 0; tS < 8; ++tS)
#pragma unroll
    for (int r = 0; r < 4; ++r) {
      float e = __expf(sacc[tS][r] - m);
      sacc[tS][r] = e;
      lsum += e;
    }
  lsum += __shfl_xor(lsum, 16);
  lsum += __shfl_xor(lsum, 32);
  linv = 1.0f / lsum;
#pragma unroll
  for (int tS = 0; tS < 8; ++tS) {
    wp[tS][0] = cvtpk_bf16(sacc[tS][0], sacc[tS][1]);
    wp[tS][1] = cvtpk_bf16(sacc[tS][2], sacc[tS][3]);
  }
}

// O = P V (P in registers, A-frags via shfl) + 1/l + residual + ReLU + store.
__device__ __forceinline__ void pv_epi(const u16* __restrict__ Vp, const u32 wp[8][2],
                                       float linv, const f32x4 ra[4],
                                       void* __restrict__ outv, bool isbf, int bb,
                                       int hh, int w, int lane, int quad, int col,
                                       int sl0, bool hiq) {
  f32x4 oacc[4];
#pragma unroll
  for (int tc = 0; tc < 4; ++tc) oacc[tc] = (f32x4){0.f, 0.f, 0.f, 0.f};
#pragma unroll
  for (int kt = 0; kt < 4; ++kt) {
    int a00 = __shfl((int)wp[2 * kt][0],     sl0);
    int a01 = __shfl((int)wp[2 * kt][1],     sl0);
    int a10 = __shfl((int)wp[2 * kt + 1][0], sl0);
    int a11 = __shfl((int)wp[2 * kt + 1][1], sl0);
    int b00 = __shfl((int)wp[2 * kt][0],     sl0 + 16);
    int b01 = __shfl((int)wp[2 * kt][1],     sl0 + 16);
    int b10 = __shfl((int)wp[2 * kt + 1][0], sl0 + 16);
    int b11 = __shfl((int)wp[2 * kt + 1][1], sl0 + 16);
    u32x4 av;
    av[0] = (u32)(hiq ? a10 : a00);
    av[1] = (u32)(hiq ? a11 : a01);
    av[2] = (u32)(hiq ? b10 : b00);
    av[3] = (u32)(hiq ? b11 : b01);
    s16x8 ap = *(const s16x8*)&av;
#pragma unroll
    for (int tc = 0; tc < 4; ++tc) {
      s16x8 bv = *(const s16x8*)(Vp + ((kt * 4 + tc) * 64 + lane) * 8);
      oacc[tc] = __builtin_amdgcn_mfma_f32_16x16x32_bf16(ap, bv, oacc[tc], 0, 0, 0);
    }
  }
  float linv_e[4];
#pragma unroll
  for (int r = 0; r < 4; ++r) linv_e[r] = __shfl(linv, quad * 4 + r);
#pragma unroll
  for (int tc = 0; tc < 4; ++tc)
#pragma unroll
    for (int r = 0; r < 4; ++r) {
      float v = oacc[tc][r] * linv_e[r] + ra[tc][r];
      v = fmaxf(v, 0.f);
      int s = w * 16 + quad * 4 + r;
      size_t idx = ((size_t)bb * S_ + s) * HD_ + hh * D_ + tc * 16 + col;
      if (isbf) ((u16*)outv)[idx] = f2bf(v);
      else      ((float*)outv)[idx] = v;
    }
}

// Stage X[bb] through LDS scratch into per-wave A-frags.
__device__ __forceinline__ void stage_x(const void* __restrict__ Xv, bool isbf, int bb,
                                        int tid, int w, int lane, u16* scratch,
                                        s16x8 xfrag[8]) {
  u32x4* xs = (u32x4*)scratch;
#pragma unroll
  for (int half = 0; half < 2; ++half) {
    int cbase = half * 2048;
#pragma unroll
    for (int k = 0; k < 4; ++k) {
      int c  = cbase + tid + k * 512;       // 8-element chunk id
      int s  = c >> 5;                      // row 0..127
      int e0 = (c & 31) * 8;                // elem base within row
      U16x8 tmp;
      if (isbf) {
        const u32x4* xg = (const u32x4*)Xv + (size_t)bb * 4096;
        u32x4 raw = xg[c];
        tmp = *(const U16x8*)&raw;
      } else {
        const f32x4* xg = (const f32x4*)Xv + (size_t)bb * 8192;
        f32x4 lo = xg[2 * c], hi = xg[2 * c + 1];
#pragma unroll
        for (int j = 0; j < 4; ++j) { tmp.v[j] = f2bf(lo[j]); tmp.v[4 + j] = f2bf(hi[j]); }
      }
      xs[(((s >> 4) & 3) * 8 + (e0 >> 5)) * 64 + ((e0 >> 3) & 3) * 16 + (s & 15)] =
          *(const u32x4*)tmp.v;
    }
    __syncthreads();
    if ((w >> 2) == half) {
      int trl = w & 3;
#pragma unroll
      for (int ks = 0; ks < 8; ++ks) {
        u32x4 raw = xs[(trl * 8 + ks) * 64 + lane];
        xfrag[ks] = *(const s16x8*)&raw;
      }
    }
    __syncthreads();
  }
}

// ---------------------------------------------------------------------------
// Fused MHA, dual-batch + weight-LDS + head-pipelined. One workgroup per TWO
// batches (grid 512), 8 waves, 1 block/CU (144 KiB LDS).
// Each weight B-frag is read from LDS once and feeds TWO batches' MFMAs
// (proj4_lds2) — halves proj LDS reads, DMA traffic, and barriers per batch.
// 4 phases per head, skewed attention:
//   P0: [DMA K(h)]  PV+epi(b1,h-1)        | proj Q(h) both -> aq0,aq1
//   P1: [DMA V(h)]  proj K(h) both -> Kb0,Kb1
//   P2: [DMA R(h)]  proj V(h) both -> Vb0,Vb1 | QK+softmax(b0,h)
//   P3: [DMA Q(h+1)] proj R(h) both -> ra0,ra1 | QK+softmax(b1,h) | PV+epi(b0,h)
// Single-buffered K/V per batch: every producer/consumer pair is separated by
// >=1 barrier (checked per buffer).
// LDS: Wb 2x32K | Qf 16K (transient, reused b0 then b1) | K 2x16K | V 2x16K.
// ---------------------------------------------------------------------------
__global__ __launch_bounds__(512) void mha_fused(
    const void* __restrict__ Xv, const u16* __restrict__ WF,
    const void* __restrict__ wqv, const void* __restrict__ wkv,
    const void* __restrict__ wvv, const void* __restrict__ wrv,
    void* __restrict__ outv, const u32* __restrict__ flag, int useWF) {
  __shared__ __align__(16) u16 smem[73728];   // 144 KiB
  u16* Wb0 = smem;               // 16384 u16 = 32 KiB
  u16* Wb1 = smem + 16384;
  u16* Qf  = smem + 32768;       // 8192
  u16* Kb0 = smem + 40960;       // 8192
  u16* Kb1 = smem + 49152;       // 8192
  u16* Vb0 = smem + 57344;       // 8192
  u16* Vb1 = smem + 65536;       // 8192

  const bool isbf = (flag[0] != 0u);
  const int tid  = threadIdx.x;
  const int w    = tid >> 6;     // wave id: owns rows [16w, 16w+16)
  const int lane = tid & 63;
  const int quad = lane >> 4;
  const int col  = lane & 15;
  const int b0i  = blockIdx.x * 2;
  const int b1i  = b0i + 1;

  // prologue DMA: slice (Q, head 0) -> Wb0 (flies under X staging)
  if (useWF) dma_w(WF, 0, Wb0, tid);

  // stage both batches' X into register A-frags (scratch = Kb region, 32 KiB)
  s16x8 xf0[8], xf1[8];
  stage_x(Xv, isbf, b0i, tid, w, lane, Kb0, xf0);
  stage_x(Xv, isbf, b1i, tid, w, lane, Kb0, xf1);

  const int sl0 = (lane & 15) | ((lane & 16) << 1);   // q + ((quad&1)?32:0)
  const bool hiq = (lane >= 32);                      // quad>>1

  // cross-iteration pipeline state (b1's attn tail runs in next head's P0)
  u32 wp1[8][2];
  float linv1 = 0.f;
  f32x4 ra1[4];

  for (int h = 0; h <= H_; ++h) {
    s16x8 aq0[2], aq1[2];

    // ================= P0: PV+epi(b1,h-1) | proj Q(h) =================
    __syncthreads();                                   // DMA(Q,h) landed
    if (useWF && h < H_) dma_w(WF, 8 + h, Wb1, tid);   // -> K(h)
    if (h > 0)
      pv_epi(Vb1, wp1, linv1, ra1, outv, isbf, b1i, h - 1, w, lane, quad, col, sl0, hiq);
    if (h == H_) break;
    {
      f32x4 a0[4], a1[4];
      if (useWF) proj4_lds2(Wb0, lane, xf0, xf1, a0, a1);
      else { proj4_direct(wqv, isbf, h, lane, xf0, a0);
             proj4_direct(wqv, isbf, h, lane, xf1, a1); }
      // Qf round-trip is intra-wave (wave writes/reads only its own rows):
      // sequential reuse of the single buffer for b0 then b1 is safe.
      scatter_qk(Qf, w, quad, col, a0);
      aq0[0] = *(const s16x8*)(Qf + ((w * 2 + 0) * 64 + lane) * 8);
      aq0[1] = *(const s16x8*)(Qf + ((w * 2 + 1) * 64 + lane) * 8);
      scatter_qk(Qf, w, quad, col, a1);
      aq1[0] = *(const s16x8*)(Qf + ((w * 2 + 0) * 64 + lane) * 8);
      aq1[1] = *(const s16x8*)(Qf + ((w * 2 + 1) * 64 + lane) * 8);
    }

    // ================= P1: proj K(h) both batches =================
    __syncthreads();                                   // DMA(K,h) landed
    if (useWF) dma_w(WF, 16 + h, Wb0, tid);            // -> V(h)
    {
      f32x4 a0[4], a1[4];
      if (useWF) proj4_lds2(Wb1, lane, xf0, xf1, a0, a1);
      else { proj4_direct(wkv, isbf, h, lane, xf0, a0);
             proj4_direct(wkv, isbf, h, lane, xf1, a1); }
      scatter_qk(Kb0, w, quad, col, a0);
      scatter_qk(Kb1, w, quad, col, a1);
    }

    // ================= P2: proj V(h) | QK+softmax(b0,h) =================
    __syncthreads();                                   // DMA(V,h) landed
    if (useWF) dma_w(WF, 24 + h, Wb1, tid);            // -> R(h)
    u32 wp0[8][2];
    float linv0 = 0.f;
    {
      f32x4 a0[4], a1[4];
      if (useWF) proj4_lds2(Wb0, lane, xf0, xf1, a0, a1);
      else { proj4_direct(wvv, isbf, h, lane, xf0, a0);
             proj4_direct(wvv, isbf, h, lane, xf1, a1); }
      scatter_v(Vb0, w, quad, col, a0);
      scatter_v(Vb1, w, quad, col, a1);
    }
    qk_sm(Kb0, aq0, lane, wp0, linv0);

    // ================= P3: proj R(h) | QK+sm(b1,h) | PV+epi(b0,h) =========
    __syncthreads();                                   // DMA(R,h) landed
    if (useWF && h + 1 < H_) dma_w(WF, h + 1, Wb0, tid);  // -> Q(h+1)
    f32x4 ra0[4];
    if (useWF) proj4_lds2(Wb1, lane, xf0, xf1, ra0, ra1);
    else { proj4_direct(wrv, isbf, h, lane, xf0, ra0);
           proj4_direct(wrv, isbf, h, lane, xf1, ra1); }
    qk_sm(Kb1, aq1, lane, wp1, linv1);
    pv_epi(Vb0, wp0, linv0, ra0, outv, isbf, b0i, h, w, lane, quad, col, sl0, hiq);
  }
}

extern "C" void kernel_launch(void* const* d_in, const int* in_sizes, int n_in,
                              void* d_out, int out_size, void* d_ws, size_t ws_size,
                              hipStream_t stream) {
  const void* X  = d_in[0];
  const void* wq = d_in[1];
  const void* wk = d_in[2];
  const void* wv = d_in[3];
  const void* wr = d_in[4];

  u32* flag = (u32*)d_ws;                       // 4 B flag at ws offset 0
  u16* wf   = (u16*)((char*)d_ws + 4096);       // 1 MiB fragment cache
  int useWF = (ws_size >= (size_t)(1u << 20) + 4096) ? 1 : 0;

  probe_dtype<<<dim3(1), dim3(256), 0, stream>>>((const u32*)X, flag);
  if (useWF)
    repack_w<<<dim3(256), dim3(256), 0, stream>>>(wq, wk, wv, wr, flag, wf);
  mha_fused<<<dim3(B_ / 2), dim3(512), 0, stream>>>(X, wf, wq, wk, wv, wr, d_out, flag, useWF);
}